// Round 16
// baseline (102.822 us; speedup 1.0000x reference)
//
#include <hip/hip_runtime.h>

#define MARGIN 0.0625f

// Problem sizes (fixed by the reference)
#define P 4096        // 64*64 query points
#define M 100000      // means

// Grid: threshold distance sqrt(MARGIN) = 0.25; cell = 0.25 so the
// 27-neighborhood of a query's (clamped) cell contains every mean with
// |q-m|inf <= 0.25, hence every mean that can have d^2 < MARGIN. Points
// outside the extent clamp into border cells; clamping is per-axis
// monotone & 1-Lipschitz so the coverage guarantee survives. Extra /
// duplicate candidates are harmless for a min; zero candidates => true
// min >= MARGIN => relu contribution 0. Bit-exact rounds 7/8/10-13/15.
#define NC 36
#define NCELLS (NC * NC * NC)   // 46656
#define GMIN (-4.5f)
#define CW 0.25f
#define INVC 4.0f               // 1 / 0.25

// Fixed-capacity buckets (ws is 256 MiB): 46656 cells x 256 x 16 B = 191 MB.
// Max observed cell count ~150 << 256; slot<CAP guard + min(cnt,CAP) keep
// accesses in-range regardless of data.
#define CAP 256

typedef float float4v __attribute__((ext_vector_type(4)));

// ws layout (bytes):
//   cnt: uint[NCELLS]          @ 0        (186,624 B; zeroed by memset)
//   bucket: float4[NCELLS*CAP] @ 186,880  (191,102,976 B)
#define WS_CNT_OFF    0
#define WS_BUCKET_OFF 186880

static __device__ __forceinline__ int cell1(float v) {
    int c = (int)floorf((v - GMIN) * INVC);
    return min(max(c, 0), NC - 1);
}

// ---------------------------------------------------------------------------
// Kernel 1: scatter means into per-cell buckets (-2x,-2y,-2z,|m|^2 --
// bit-identical transform chain to all prior rounds). Identical to the
// round-11 scatter (passed at 93.6 us).
// Also zeroes out[0] (stream-ordered before query_kernel's atomicAdds).
// ---------------------------------------------------------------------------
__global__ __launch_bounds__(256) void scatter_kernel(
    const float* __restrict__ means,
    unsigned int* __restrict__ cnt,
    float4v* __restrict__ bucket,
    float* __restrict__ out)
{
    int idx = blockIdx.x * 256 + threadIdx.x;
    if (idx == 0) out[0] = 0.0f;
    if (idx < M) {
        const float* mp = means + 3 * idx;
        float x = mp[0], y = mp[1], z = mp[2];
        int c = (cell1(z) * NC + cell1(y)) * NC + cell1(x);
        unsigned int slot = atomicAdd(&cnt[c], 1u);
        if (slot < CAP)
            bucket[(size_t)c * CAP + slot] =
                (float4v){-2.0f * x, -2.0f * y, -2.0f * z,
                          fmaf(x, x, fmaf(y, y, z * z))};
    }
}

// Per-axis box distance for the (clamped) neighbor cell kk. Border cells'
// boxes extend to +-inf on the clamped side, so means clamped INTO border
// cells (coord outside [-4.5,4.5]) keep a valid lower bound.
static __device__ __forceinline__ float axdist(float q, int kk) {
    float lo = (kk == 0)      ? -1e30f : GMIN + kk * CW;
    float hi = (kk == NC - 1) ?  1e30f : GMIN + (kk + 1) * CW;
    return fmaxf(fmaxf(lo - q, q - hi), 0.0f);
}

// ---------------------------------------------------------------------------
// Kernel 2: query + loss. Round-11 shell (1 wave/query, 4 queries/block,
// XCD chunk swizzle, (256,4), 27-count single-group prefetch) with the
// gathers DE-BRANCHED (round-15 lesson: per-cell `if(n==0) continue`
// serialized up to 27 HBM-latency exposures per wave; lb-pruning couldn't
// help the dense-center tail because those cells all pass).
//   round 0: unconditional gather row[min(lane, max(n-1,0))] for all 27
//     cells -> ONE issue group, one latency exposure. For n==0 this reads
//     slot 0 (in-bounds poison, 1 broadcast line); the result is replaced
//     by 1e30f via select BEFORE the min -> exact, no NaN propagation.
//     For n>0 the clamped slot is a written slot -> duplicate candidate,
//     exact for min (validated since round 10).
//   round 1 (slots 64+lane): second branch-free group, gated by a single
//     wave-uniform maxn>64 so sparse queries skip it entirely.
//   round 2 (n>128): rare dense cells, branchy as before.
// lb-pruning retained (zero-cost: folds into n=0 -> select mask).
// Per-pair fmaf chain identical to all prior rounds.
// ---------------------------------------------------------------------------
__global__ __launch_bounds__(256, 4) void query_kernel(
    const float* __restrict__ outputs,   // [P*3]
    const float* __restrict__ c2ws,      // [64*16]
    const float* __restrict__ scales,    // [64]
    const unsigned int* __restrict__ cnt,
    const float4v* __restrict__ bucket,
    float* __restrict__ out)
{
    const int t    = threadIdx.x;
    const int lane = t & 63;
    // 1024 blocks = 8 XCDs x 128: chunk consecutive qb onto one XCD so
    // same-trajectory queries (shared cells) hit the same L2.
    const int bid = (int)blockIdx.x;
    const int qb  = (bid & 7) * 128 + (bid >> 3);
    const int qi  = qb * 4 + (t >> 6);

    // ---- query transform (all lanes redundantly; scalar-broadcast) ----
    const int b = qi >> 6;
    const float s  = scales[b];
    const float o0 = outputs[3 * qi + 0];
    const float o1 = outputs[3 * qi + 1];
    const float o2 = outputs[3 * qi + 2];
    const float* cw = c2ws + b * 16;
    float q0 = fmaf(s, fmaf(cw[0],  o0, fmaf(cw[1],  o1, cw[2]  * o2)), cw[3]);
    float q1 = fmaf(s, fmaf(cw[4],  o0, fmaf(cw[5],  o1, cw[6]  * o2)), cw[7]);
    float q2 = fmaf(s, fmaf(cw[8],  o0, fmaf(cw[9],  o1, cw[10] * o2)), cw[11]);
    float qq = fmaf(q0, q0, fmaf(q1, q1, q2 * q2));

    const int cx = cell1(q0), cy = cell1(q1), cz = cell1(q2);

    // per-axis clamped neighbor indices + squared box distances
    int   kx[3], ky[3], kz[3];
    float dx2[3], dy2[3], dz2[3];
#pragma unroll
    for (int o = 0; o < 3; ++o) {
        kx[o] = min(max(cx + o - 1, 0), NC - 1);
        ky[o] = min(max(cy + o - 1, 0), NC - 1);
        kz[o] = min(max(cz + o - 1, 0), NC - 1);
        float ax = axdist(q0, kx[o]); dx2[o] = ax * ax;
        float ay = axdist(q1, ky[o]); dy2[o] = ay * ay;
        float az = axdist(q2, kz[o]); dz2[o] = az * az;
    }

    // ---- prefetch all 27 cell ids + counts (independent loads, one
    // wait); lb-pruned cells get n=0 (their gather is select-masked).
    int c27[27];
#pragma unroll
    for (int j = 0; j < 27; ++j) {
        const int iz = j / 9, iy = (j / 3) % 3, ix = j % 3;   // static
        c27[j] = (kz[iz] * NC + ky[iy]) * NC + kx[ix];
    }
    int n27[27];
#pragma unroll
    for (int j = 0; j < 27; ++j) {
        const int iz = j / 9, iy = (j / 3) % 3, ix = j % 3;   // static
        const float lb = dz2[iz] + dy2[iy] + dx2[ix];
        n27[j] = (lb < MARGIN) ? min((int)cnt[c27[j]], CAP) : 0;
    }

    int tot = 0, maxn = 0;
#pragma unroll
    for (int j = 0; j < 27; ++j) { tot += n27[j]; maxn = max(maxn, n27[j]); }

    float mnA = 1e30f, mnB = 1e30f;
    if (tot > 0) {      // wave-uniform (all inputs identical across lanes)
        // ---- round 0: 27 branch-free gathers, one issue group ----
#pragma unroll
        for (int j = 0; j < 27; ++j) {
            const int n = n27[j];
            const float4v* row = bucket + (size_t)c27[j] * CAP;
            float4v mv = row[min(lane, max(n - 1, 0))];
            float d = fmaf(q2, mv[2], fmaf(q1, mv[1],
                      fmaf(q0, mv[0], mv[3])));
            d = (n > 0) ? d : 1e30f;               // mask empty/pruned
            if (j & 1) mnB = fminf(mnB, d); else mnA = fminf(mnA, d);
        }
        // ---- round 1: slots 64..127, branch-free, wave-uniform gate ----
        if (maxn > 64) {
#pragma unroll
            for (int j = 0; j < 27; ++j) {
                const int n = n27[j];
                const float4v* row = bucket + (size_t)c27[j] * CAP;
                float4v mv = row[min(64 + lane, max(n - 1, 0))];
                float d = fmaf(q2, mv[2], fmaf(q1, mv[1],
                          fmaf(q0, mv[0], mv[3])));
                d = (n > 0) ? d : 1e30f;           // n<=64: dup slot, exact
                if (j & 1) mnB = fminf(mnB, d); else mnA = fminf(mnA, d);
            }
        }
        // ---- round 2: rare dense cells (n>128), branchy ----
        if (maxn > 128) {
#pragma unroll
            for (int j = 0; j < 27; ++j) {
                const int n = n27[j];
                if (n > 128) {                     // wave-uniform
                    const float4v* row = bucket + (size_t)c27[j] * CAP;
                    for (int k = 128 + lane; k < n; k += 64) {
                        float4v mv = row[k];
                        mnA = fminf(mnA, fmaf(q2, mv[2], fmaf(q1, mv[1],
                                        fmaf(q0, mv[0], mv[3]))));
                    }
                }
            }
        }
    }

    float mn = fminf(mnA, mnB);
    // ---- fold 64 lanes ----
#pragma unroll
    for (int off = 32; off > 0; off >>= 1)
        mn = fminf(mn, __shfl_xor(mn, off, 64));

    float v = 0.0f;
    if (lane == 0) {
        float d = fmaxf(qq + mn, 0.0f);   // empty neighborhood -> relu 0
        v = fmaxf(MARGIN - d, 0.0f) * (1.0f / (float)P);
    }

    // ---- block reduction (4 wave leaders), one atomicAdd per block ----
    __shared__ float red[4];
    if (lane == 0) red[t >> 6] = v;
    __syncthreads();
    if (t == 0)
        atomicAdd(out, red[0] + red[1] + red[2] + red[3]);
}

extern "C" void kernel_launch(void* const* d_in, const int* in_sizes, int n_in,
                              void* d_out, int out_size, void* d_ws, size_t ws_size,
                              hipStream_t stream) {
    const float* outputs = (const float*)d_in[0];  // (64,64,3)
    const float* c2ws    = (const float*)d_in[1];  // (64,4,4)
    const float* scales  = (const float*)d_in[2];  // (64,)
    const float* means   = (const float*)d_in[3];  // (100000,3)

    char* ws = (char*)d_ws;
    unsigned int* cnt    = (unsigned int*)(ws + WS_CNT_OFF);
    float4v*      bucket = (float4v*)(ws + WS_BUCKET_OFF);
    float*        out    = (float*)d_out;

    hipMemsetAsync(cnt, 0, NCELLS * sizeof(unsigned int), stream);
    scatter_kernel<<<(M + 255) / 256, 256, 0, stream>>>(means, cnt, bucket, out);
    query_kernel<<<P / 4, 256, 0, stream>>>(outputs, c2ws, scales,
                                            cnt, bucket, out);
}

// Round 17
// 94.251 us; speedup vs baseline: 1.0909x; 1.0909x over previous
//
#include <hip/hip_runtime.h>

#define MARGIN 0.0625f

// Problem sizes (fixed by the reference)
#define P 4096        // 64*64 query points
#define M 100000      // means

// Grid: threshold distance sqrt(MARGIN) = 0.25; cell = 0.25 so the
// 27-neighborhood of a query's (clamped) cell contains every mean with
// |q-m|inf <= 0.25, hence every mean that can have d^2 < MARGIN. Points
// outside the extent clamp into border cells; clamping is per-axis
// monotone & 1-Lipschitz so the coverage guarantee survives. Extra /
// duplicate candidates are harmless for a min; zero candidates => true
// min >= MARGIN => relu contribution 0. Bit-exact rounds 7/8/10-13/15/16.
#define NC 36
#define NCELLS (NC * NC * NC)   // 46656
#define GMIN (-4.5f)
#define CW 0.25f
#define INVC 4.0f               // 1 / 0.25

// Fixed-capacity buckets (ws is 256 MiB): 46656 cells x 256 x 16 B = 191 MB.
// Max observed cell count ~150 << 256; slot<CAP guard + min(cnt,CAP) keep
// accesses in-range regardless of data.
#define CAP 256

typedef float float4v __attribute__((ext_vector_type(4)));

// ws layout (bytes):
//   cnt: uint[NCELLS]          @ 0        (186,624 B; zeroed by memset)
//   bucket: float4[NCELLS*CAP] @ 186,880  (191,102,976 B)
#define WS_CNT_OFF    0
#define WS_BUCKET_OFF 186880

static __device__ __forceinline__ int cell1(float v) {
    int c = (int)floorf((v - GMIN) * INVC);
    return min(max(c, 0), NC - 1);
}

// ---------------------------------------------------------------------------
// Kernel 1: scatter means into per-cell buckets (-2x,-2y,-2z,|m|^2 --
// bit-identical transform chain to all prior rounds; identical to the
// round-11 scatter). Also zeroes out[0] (stream-ordered before query).
// ---------------------------------------------------------------------------
__global__ __launch_bounds__(256) void scatter_kernel(
    const float* __restrict__ means,
    unsigned int* __restrict__ cnt,
    float4v* __restrict__ bucket,
    float* __restrict__ out)
{
    int idx = blockIdx.x * 256 + threadIdx.x;
    if (idx == 0) out[0] = 0.0f;
    if (idx < M) {
        const float* mp = means + 3 * idx;
        float x = mp[0], y = mp[1], z = mp[2];
        int c = (cell1(z) * NC + cell1(y)) * NC + cell1(x);
        unsigned int slot = atomicAdd(&cnt[c], 1u);
        if (slot < CAP)
            bucket[(size_t)c * CAP + slot] =
                (float4v){-2.0f * x, -2.0f * y, -2.0f * z,
                          fmaf(x, x, fmaf(y, y, z * z))};
    }
}

// Per-axis box distance for the (clamped) neighbor cell kk. Border cells'
// boxes extend to +-inf on the clamped side, so means clamped INTO border
// cells (coord outside [-4.5,4.5]) keep a valid lower bound.
static __device__ __forceinline__ float axdist(float q, int kk) {
    float lo = (kk == 0)      ? -1e30f : GMIN + kk * CW;
    float hi = (kk == NC - 1) ?  1e30f : GMIN + (kk + 1) * CW;
    return fmaxf(fmaxf(lo - q, q - hi), 0.0f);
}

// ---------------------------------------------------------------------------
// Kernel 2: query + loss. Round-11 shell (1 wave/query, 4 queries/block,
// XCD chunk swizzle, (256,4), 27-count single-group prefetch, lb-pruning)
// with gathers issued in GROUPS OF 3 (one x-row per group, 9 groups).
// r11 (fully branchy): up to 27 serial latency exposures. r16 (fully
// branch-free): 1-2 exposures but 27-54 unconditional gathers (3x traffic
// for sparse queries; regressed). This round: per group, the 3 loads are
// CONDITIONAL (no extra traffic) but the uses are UNCONDITIONAL via
// neutral-init mv = (0,0,0,1e30f) -> d == 1e30 exactly for skipped cells
// (q finite => fma(q,0,...) chain exact), a no-op for fminf. Loads can't
// be merged into the use blocks (no shared condition around uses), so the
// 3 loads issue back-to-back: ONE exposure per group, ~9 per wave.
// Empty groups skipped wave-uniformly. Per-pair fmaf chain identical to
// all prior rounds.
// ---------------------------------------------------------------------------
__global__ __launch_bounds__(256, 4) void query_kernel(
    const float* __restrict__ outputs,   // [P*3]
    const float* __restrict__ c2ws,      // [64*16]
    const float* __restrict__ scales,    // [64]
    const unsigned int* __restrict__ cnt,
    const float4v* __restrict__ bucket,
    float* __restrict__ out)
{
    const int t    = threadIdx.x;
    const int lane = t & 63;
    // 1024 blocks = 8 XCDs x 128: chunk consecutive qb onto one XCD.
    const int bid = (int)blockIdx.x;
    const int qb  = (bid & 7) * 128 + (bid >> 3);
    const int qi  = qb * 4 + (t >> 6);

    // ---- query transform (all lanes redundantly; scalar-broadcast) ----
    const int b = qi >> 6;
    const float s  = scales[b];
    const float o0 = outputs[3 * qi + 0];
    const float o1 = outputs[3 * qi + 1];
    const float o2 = outputs[3 * qi + 2];
    const float* cw = c2ws + b * 16;
    float q0 = fmaf(s, fmaf(cw[0],  o0, fmaf(cw[1],  o1, cw[2]  * o2)), cw[3]);
    float q1 = fmaf(s, fmaf(cw[4],  o0, fmaf(cw[5],  o1, cw[6]  * o2)), cw[7]);
    float q2 = fmaf(s, fmaf(cw[8],  o0, fmaf(cw[9],  o1, cw[10] * o2)), cw[11]);
    float qq = fmaf(q0, q0, fmaf(q1, q1, q2 * q2));

    const int cx = cell1(q0), cy = cell1(q1), cz = cell1(q2);

    // per-axis clamped neighbor indices + squared box distances
    int   kx[3], ky[3], kz[3];
    float dx2[3], dy2[3], dz2[3];
#pragma unroll
    for (int o = 0; o < 3; ++o) {
        kx[o] = min(max(cx + o - 1, 0), NC - 1);
        ky[o] = min(max(cy + o - 1, 0), NC - 1);
        kz[o] = min(max(cz + o - 1, 0), NC - 1);
        float ax = axdist(q0, kx[o]); dx2[o] = ax * ax;
        float ay = axdist(q1, ky[o]); dy2[o] = ay * ay;
        float az = axdist(q2, kz[o]); dz2[o] = az * az;
    }

    // ---- prefetch all 27 cell ids + counts (independent loads, one
    // wait); lb-pruned cells get n=0.
    int c27[27];
#pragma unroll
    for (int j = 0; j < 27; ++j) {
        const int iz = j / 9, iy = (j / 3) % 3, ix = j % 3;   // static
        c27[j] = (kz[iz] * NC + ky[iy]) * NC + kx[ix];
    }
    int n27[27];
#pragma unroll
    for (int j = 0; j < 27; ++j) {
        const int iz = j / 9, iy = (j / 3) % 3, ix = j % 3;   // static
        const float lb = dz2[iz] + dy2[iy] + dx2[ix];
        n27[j] = (lb < MARGIN) ? min((int)cnt[c27[j]], CAP) : 0;
    }

#define NEUT ((float4v){0.0f, 0.0f, 0.0f, 1e30f})
#define DVAL(mv) fmaf(q2, (mv)[2], fmaf(q1, (mv)[1], fmaf(q0, (mv)[0], (mv)[3])))

    float mnA = 1e30f, mnB = 1e30f;
#pragma unroll
    for (int g = 0; g < 9; ++g) {
        const int j0 = g * 3;                       // static
        const int n0 = n27[j0], n1 = n27[j0 + 1], n2 = n27[j0 + 2];
        if ((n0 | n1 | n2) > 0) {                   // wave-uniform
            const float4v* r0 = bucket + (size_t)c27[j0]     * CAP;
            const float4v* r1 = bucket + (size_t)c27[j0 + 1] * CAP;
            const float4v* r2 = bucket + (size_t)c27[j0 + 2] * CAP;
            // round 0: conditional loads (no extra traffic), issued
            // back-to-back; unconditional neutral-masked uses.
            float4v mv0 = NEUT, mv1 = NEUT, mv2 = NEUT;
            if (n0 > 0) mv0 = r0[min(lane, n0 - 1)];
            if (n1 > 0) mv1 = r1[min(lane, n1 - 1)];
            if (n2 > 0) mv2 = r2[min(lane, n2 - 1)];
            mnA = fminf(mnA, DVAL(mv0));
            mnB = fminf(mnB, DVAL(mv1));
            mnA = fminf(mnA, DVAL(mv2));
            // round 1: slots 64.., same pattern (clamped dup slots exact)
            if ((n0 > 64) | (n1 > 64) | (n2 > 64)) {    // wave-uniform
                float4v w0 = NEUT, w1 = NEUT, w2 = NEUT;
                if (n0 > 64) w0 = r0[min(64 + lane, n0 - 1)];
                if (n1 > 64) w1 = r1[min(64 + lane, n1 - 1)];
                if (n2 > 64) w2 = r2[min(64 + lane, n2 - 1)];
                mnA = fminf(mnA, DVAL(w0));
                mnB = fminf(mnB, DVAL(w1));
                mnA = fminf(mnA, DVAL(w2));
            }
            // round 2: rare dense cells (n>128), branchy
            if ((n0 > 128) | (n1 > 128) | (n2 > 128)) { // wave-uniform
                if (n0 > 128)
                    for (int k = 128 + lane; k < n0; k += 64)
                        mnA = fminf(mnA, DVAL(r0[k]));
                if (n1 > 128)
                    for (int k = 128 + lane; k < n1; k += 64)
                        mnB = fminf(mnB, DVAL(r1[k]));
                if (n2 > 128)
                    for (int k = 128 + lane; k < n2; k += 64)
                        mnA = fminf(mnA, DVAL(r2[k]));
            }
        }
    }
#undef NEUT
#undef DVAL

    float mn = fminf(mnA, mnB);
    // ---- fold 64 lanes ----
#pragma unroll
    for (int off = 32; off > 0; off >>= 1)
        mn = fminf(mn, __shfl_xor(mn, off, 64));

    float v = 0.0f;
    if (lane == 0) {
        float d = fmaxf(qq + mn, 0.0f);   // empty neighborhood -> relu 0
        v = fmaxf(MARGIN - d, 0.0f) * (1.0f / (float)P);
    }

    // ---- block reduction (4 wave leaders), one atomicAdd per block ----
    __shared__ float red[4];
    if (lane == 0) red[t >> 6] = v;
    __syncthreads();
    if (t == 0)
        atomicAdd(out, red[0] + red[1] + red[2] + red[3]);
}

extern "C" void kernel_launch(void* const* d_in, const int* in_sizes, int n_in,
                              void* d_out, int out_size, void* d_ws, size_t ws_size,
                              hipStream_t stream) {
    const float* outputs = (const float*)d_in[0];  // (64,64,3)
    const float* c2ws    = (const float*)d_in[1];  // (64,4,4)
    const float* scales  = (const float*)d_in[2];  // (64,)
    const float* means   = (const float*)d_in[3];  // (100000,3)

    char* ws = (char*)d_ws;
    unsigned int* cnt    = (unsigned int*)(ws + WS_CNT_OFF);
    float4v*      bucket = (float4v*)(ws + WS_BUCKET_OFF);
    float*        out    = (float*)d_out;

    hipMemsetAsync(cnt, 0, NCELLS * sizeof(unsigned int), stream);
    scatter_kernel<<<(M + 255) / 256, 256, 0, stream>>>(means, cnt, bucket, out);
    query_kernel<<<P / 4, 256, 0, stream>>>(outputs, c2ws, scales,
                                            cnt, bucket, out);
}